// Round 1
// baseline (179.190 us; speedup 1.0000x reference)
//
#include <hip/hip_runtime.h>

// Problem dims (fixed by reference)
#define BDIM 32
#define SDIM 256
#define TOK_TOTAL (BDIM * SDIM)   // 8192
#define DDIM 512
#define HDIM 256
#define ODIM 2
#define NHEADS 16
#define VOCAB 1024

#define CHUNKS 16
#define CHUNK (TOK_TOTAL / CHUNKS)  // 512 tokens per block's scan range
#define TILE 32                     // tokens per compute tile
#define KB 16                       // K-chunk staged in LDS

__global__ __launch_bounds__(256) void mth_routed_fp32(
    const float* __restrict__ X,      // [8192, 512]
    const int*   __restrict__ tasks,  // [8192]
    const int*   __restrict__ lut,    // [1024]
    const float* __restrict__ W1,     // [16, 512, 256]
    const float* __restrict__ b1,     // [16, 256]
    const float* __restrict__ W2,     // [16, 256, 256]
    const float* __restrict__ b2,     // [16, 256]
    const float* __restrict__ W3,     // [16, 256, 2]
    const float* __restrict__ b3,     // [16, 2]
    float* __restrict__ out)          // [8192, 2]
{
    const int n    = blockIdx.x;   // head
    const int chnk = blockIdx.y;
    const int tid  = threadIdx.x;
    const int lane = tid & 63;
    const int wv   = tid >> 6;     // wave id 0..3
    const int tx   = tid & 31;     // h-group: columns tx*8 .. tx*8+7
    const int ty   = tid >> 5;     // token-group: tokens ty*4 .. ty*4+3

    __shared__ int s_list[CHUNK];
    __shared__ int s_cnt[8];
    __shared__ __align__(16) float s_x[KB][TILE];    // x chunk, [d][t]
    __shared__ __align__(16) float s_w[KB][HDIM];    // weight chunk, [d][h]
    __shared__ __align__(16) float s_h[HDIM][TILE];  // h1 transposed, [h][t]

    // ---------------- compaction: tokens of this chunk routed to head n ----
    const int base = chnk * CHUNK;
    int  mytok[2], mypre[2], myseg[2];
    bool mymatch[2];
    #pragma unroll
    for (int i = 0; i < 2; ++i) {
        const int tok  = base + i * 256 + tid;
        const int task = tasks[tok];
        const int hidx = (task >= 0 && task < VOCAB) ? lut[task] : -1;
        const bool match = (hidx == n);
        const unsigned long long mask = __ballot(match);
        mytok[i]   = tok;
        mymatch[i] = match;
        mypre[i]   = __popcll(mask & ((1ULL << lane) - 1ULL));
        myseg[i]   = i * 4 + wv;
        if (lane == 0) s_cnt[i * 4 + wv] = (int)__popcll(mask);
    }
    __syncthreads();
    int total = 0;
    int myoff[2] = {0, 0};
    #pragma unroll
    for (int s2 = 0; s2 < 8; ++s2) {
        if (s2 == myseg[0]) myoff[0] = total;
        if (s2 == myseg[1]) myoff[1] = total;
        total += s_cnt[s2];
    }
    #pragma unroll
    for (int i = 0; i < 2; ++i)
        if (mymatch[i]) s_list[myoff[i] + mypre[i]] = mytok[i];
    __syncthreads();
    const int ntok = total;
    if (ntok == 0) return;

    // ---------------- per-thread constants ---------------------------------
    float bias1[8], bias2[8];
    #pragma unroll
    for (int j = 0; j < 8; ++j) {
        bias1[j] = b1[n * HDIM + tx * 8 + j];
        bias2[j] = b2[n * HDIM + tx * 8 + j];
    }
    float w3v[16];  // [j][o] for k = tx*8+j
    #pragma unroll
    for (int j = 0; j < 16; ++j)
        w3v[j] = W3[n * HDIM * ODIM + tx * 8 * ODIM + j];
    const float b3v0 = b3[n * ODIM + 0];
    const float b3v1 = b3[n * ODIM + 1];

    const float* W1n = W1 + (size_t)n * DDIM * HDIM;
    const float* W2n = W2 + (size_t)n * HDIM * HDIM;

    // ---------------- tile loop --------------------------------------------
    for (int ts = 0; ts < ntok; ts += TILE) {
        const int m = min(TILE, ntok - ts);

        // ---- layer 1: h1 = relu(X @ W1[n] + b1) ----
        float acc[4][8];
        #pragma unroll
        for (int t = 0; t < 4; ++t)
            #pragma unroll
            for (int j = 0; j < 8; ++j) acc[t][j] = 0.f;

        for (int kc = 0; kc < DDIM / KB; ++kc) {
            // stage weight chunk (contiguous 16KB)
            const float4* src = (const float4*)(W1n + kc * KB * HDIM);
            float4* dst = (float4*)s_w;
            #pragma unroll
            for (int p = 0; p < 4; ++p) dst[tid + p * 256] = src[tid + p * 256];
            // stage x chunk (gathered)
            #pragma unroll
            for (int p = 0; p < 2; ++p) {
                const int e  = tid + p * 256;
                const int dd = e >> 5, t = e & 31;
                float v = 0.f;
                if (t < m) {
                    const int tok = s_list[ts + t];
                    v = X[(size_t)tok * DDIM + kc * KB + dd];
                }
                s_x[dd][t] = v;
            }
            __syncthreads();
            #pragma unroll
            for (int dd = 0; dd < KB; ++dd) {
                const float4 xa = *(const float4*)&s_x[dd][ty * 4];
                const float4 wa = *(const float4*)&s_w[dd][tx * 8];
                const float4 wb = *(const float4*)&s_w[dd][tx * 8 + 4];
                const float xs[4] = {xa.x, xa.y, xa.z, xa.w};
                const float ws[8] = {wa.x, wa.y, wa.z, wa.w, wb.x, wb.y, wb.z, wb.w};
                #pragma unroll
                for (int t = 0; t < 4; ++t)
                    #pragma unroll
                    for (int j = 0; j < 8; ++j)
                        acc[t][j] = fmaf(xs[t], ws[j], acc[t][j]);
            }
            __syncthreads();
        }
        // relu + bias; write h1 transposed into s_h
        #pragma unroll
        for (int j = 0; j < 8; ++j) {
            float4 v;
            v.x = fmaxf(acc[0][j] + bias1[j], 0.f);
            v.y = fmaxf(acc[1][j] + bias1[j], 0.f);
            v.z = fmaxf(acc[2][j] + bias1[j], 0.f);
            v.w = fmaxf(acc[3][j] + bias1[j], 0.f);
            *(float4*)&s_h[tx * 8 + j][ty * 4] = v;
        }
        __syncthreads();

        // ---- layer 2: h2 = relu(h1 @ W2[n] + b2) ----
        float acc2[4][8];
        #pragma unroll
        for (int t = 0; t < 4; ++t)
            #pragma unroll
            for (int j = 0; j < 8; ++j) acc2[t][j] = 0.f;

        for (int kc = 0; kc < HDIM / KB; ++kc) {
            const float4* src = (const float4*)(W2n + kc * KB * HDIM);
            float4* dst = (float4*)s_w;
            #pragma unroll
            for (int p = 0; p < 4; ++p) dst[tid + p * 256] = src[tid + p * 256];
            __syncthreads();
            #pragma unroll
            for (int dd = 0; dd < KB; ++dd) {
                const int k = kc * KB + dd;
                const float4 xa = *(const float4*)&s_h[k][ty * 4];
                const float4 wa = *(const float4*)&s_w[dd][tx * 8];
                const float4 wb = *(const float4*)&s_w[dd][tx * 8 + 4];
                const float xs[4] = {xa.x, xa.y, xa.z, xa.w};
                const float ws[8] = {wa.x, wa.y, wa.z, wa.w, wb.x, wb.y, wb.z, wb.w};
                #pragma unroll
                for (int t = 0; t < 4; ++t)
                    #pragma unroll
                    for (int j = 0; j < 8; ++j)
                        acc2[t][j] = fmaf(xs[t], ws[j], acc2[t][j]);
            }
            __syncthreads();
        }

        // ---- layer 3: out = h2 @ W3[n] + b3 (O=2), half-wave reduction ----
        float p0[4] = {0.f, 0.f, 0.f, 0.f};
        float p1[4] = {0.f, 0.f, 0.f, 0.f};
        #pragma unroll
        for (int t = 0; t < 4; ++t) {
            #pragma unroll
            for (int j = 0; j < 8; ++j) {
                const float v = fmaxf(acc2[t][j] + bias2[j], 0.f);
                p0[t] = fmaf(v, w3v[j * 2 + 0], p0[t]);
                p1[t] = fmaf(v, w3v[j * 2 + 1], p1[t]);
            }
        }
        #pragma unroll
        for (int off = 16; off > 0; off >>= 1) {
            #pragma unroll
            for (int t = 0; t < 4; ++t) {
                p0[t] += __shfl_xor(p0[t], off);
                p1[t] += __shfl_xor(p1[t], off);
            }
        }
        if (tx == 0) {
            #pragma unroll
            for (int t = 0; t < 4; ++t) {
                const int ti = ty * 4 + t;
                if (ti < m) {
                    const int tok = s_list[ts + ti];
                    out[tok * ODIM + 0] = p0[t] + b3v0;
                    out[tok * ODIM + 1] = p1[t] + b3v1;
                }
            }
        }
        __syncthreads();
    }
}

extern "C" void kernel_launch(void* const* d_in, const int* in_sizes, int n_in,
                              void* d_out, int out_size, void* d_ws, size_t ws_size,
                              hipStream_t stream) {
    const float* X     = (const float*)d_in[0];
    const int*   tasks = (const int*)d_in[1];
    const int*   lut   = (const int*)d_in[2];
    const float* W1    = (const float*)d_in[3];
    const float* b1    = (const float*)d_in[4];
    const float* W2    = (const float*)d_in[5];
    const float* b2    = (const float*)d_in[6];
    const float* W3    = (const float*)d_in[7];
    const float* b3    = (const float*)d_in[8];
    float* out = (float*)d_out;

    // zero output (covers invalid/unwritten tokens; capture-safe)
    hipMemsetAsync(out, 0, (size_t)out_size * sizeof(float), stream);

    dim3 grid(NHEADS, CHUNKS);
    mth_routed_fp32<<<grid, 256, 0, stream>>>(X, tasks, lut, W1, b1, W2, b2, W3, b3, out);
}

// Round 2
// 137.649 us; speedup vs baseline: 1.3018x; 1.3018x over previous
//
#include <hip/hip_runtime.h>

#define TOK_TOTAL 8192
#define DDIM 512
#define HDIM 256
#define ODIM 2
#define NHEADS 16
#define VOCAB 1024

typedef __attribute__((ext_vector_type(8))) short short8;
typedef __attribute__((ext_vector_type(4))) float f32x4;

__device__ inline ushort f2bf(float f) {
    uint u = __float_as_uint(f);
    uint r = (u + 0x7fffu + ((u >> 16) & 1u)) >> 16;
    return (ushort)r;
}
__device__ inline float bf2f(ushort h) { return __uint_as_float(((uint)h) << 16); }

// ---------------------------------------------------------------- prep ----
// Split W1/W2 fp32 -> bf16 hi/lo planes in B-fragment order [n][kc][c][k%32].
__global__ __launch_bounds__(256) void mth_prep(
    const float* __restrict__ W1, const float* __restrict__ W2,
    ushort* __restrict__ W1h, ushort* __restrict__ W1l,
    ushort* __restrict__ W2h, ushort* __restrict__ W2l)
{
    const int tid = blockIdx.x * 256 + threadIdx.x;
    const int NW1 = NHEADS * DDIM * HDIM;  // 2M
    if (tid < NW1) {
        const int ks = tid & 31, c = (tid >> 5) & 255, kc = (tid >> 13) & 15, n = tid >> 17;
        const float x = W1[((size_t)(n * DDIM) + kc * 32 + ks) * HDIM + c];
        const ushort hi = f2bf(x);
        W1h[tid] = hi;
        W1l[tid] = f2bf(x - bf2f(hi));
    } else {
        const int t2 = tid - NW1;
        const int ks = t2 & 31, c = (t2 >> 5) & 255, kc = (t2 >> 13) & 7, n = t2 >> 16;
        const float x = W2[((size_t)(n * HDIM) + kc * 32 + ks) * HDIM + c];
        const ushort hi = f2bf(x);
        W2h[t2] = hi;
        W2l[t2] = f2bf(x - bf2f(hi));
    }
}

// ------------------------------------------------------------- compact ----
__global__ __launch_bounds__(256) void mth_compact(
    const int* __restrict__ tasks, const int* __restrict__ lut,
    int* __restrict__ counts, int* __restrict__ lists)
{
    const int tok = blockIdx.x * 256 + threadIdx.x;
    const int l = threadIdx.x & 63;
    const int task = tasks[tok];
    const int h = (task >= 0 && task < VOCAB) ? lut[task] : -1;
    const unsigned long long lt = (1ULL << l) - 1ULL;
    for (int n = 0; n < NHEADS; ++n) {
        const unsigned long long m = __ballot(h == n);
        if (m == 0ULL) continue;
        const int leader = (int)__ffsll((unsigned long long)m) - 1;
        int base = 0;
        if (l == leader) base = atomicAdd(&counts[n], (int)__popcll(m));
        base = __shfl(base, leader);
        if (h == n) lists[n * TOK_TOTAL + base + (int)__popcll(m & lt)] = tok;
    }
}

// ----------------------------------------------------------------- mlp ----
// One wave per 16-token tile of one head. Grid (16 heads, 128); 4 waves/block,
// each wave independent (no __syncthreads). LDS: per-wave h1 hi/lo planes.
__global__ __launch_bounds__(256) void mth_mfma(
    const float* __restrict__ X, const int* __restrict__ counts,
    const int* __restrict__ lists,
    const ushort* __restrict__ W1h, const ushort* __restrict__ W1l,
    const ushort* __restrict__ W2h, const ushort* __restrict__ W2l,
    const float* __restrict__ b1, const float* __restrict__ b2,
    const float* __restrict__ W3, const float* __restrict__ b3,
    float* __restrict__ out)
{
    __shared__ ushort sh1[4][2][16 * 256];  // [wave][hi/lo][row][col], 64 KB

    const int n   = blockIdx.x;
    const int tid = threadIdx.x;
    const int wv  = tid >> 6;
    const int l   = tid & 63;
    const int r16 = l & 15;   // A-row / B-col within 16-tile
    const int kg  = l >> 4;   // k-group (8 elems each)

    const int cnt = counts[n];
    const int tbase = (blockIdx.y * 4 + wv) * 16;
    if (tbase >= cnt) return;

    const int ridx = min(tbase + r16, cnt - 1);
    const int tok = lists[n * TOK_TOTAL + ridx];
    const float* xr = X + (size_t)tok * DDIM;

    const int laneB = r16 * 32 + kg * 8;
    const ushort* w1h = W1h + n * (16 * 256 * 32);
    const ushort* w1l = W1l + n * (16 * 256 * 32);

    float bias1v[16];
    #pragma unroll
    for (int t = 0; t < 16; ++t) bias1v[t] = b1[n * HDIM + t * 16 + r16];

    // ---- layer 1: h1 = relu(X W1 + b1), split-bf16 3-pass MFMA ----
    f32x4 acc[16];
    #pragma unroll
    for (int t = 0; t < 16; ++t) acc[t] = (f32x4){0.f, 0.f, 0.f, 0.f};

    for (int kc = 0; kc < 16; ++kc) {
        const float* xp = xr + kc * 32 + kg * 8;
        float xv[8];
        *(float4*)&xv[0] = *(const float4*)(xp);
        *(float4*)&xv[4] = *(const float4*)(xp + 4);
        short8 ahi, alo;
        #pragma unroll
        for (int j = 0; j < 8; ++j) {
            const ushort h = f2bf(xv[j]);
            ahi[j] = (short)h;
            alo[j] = (short)f2bf(xv[j] - bf2f(h));
        }
        const int kbase = kc * 8192 + laneB;
        #pragma unroll
        for (int t = 0; t < 16; ++t) {
            const short8 bhi = *(const short8*)(w1h + kbase + t * 512);
            const short8 blo = *(const short8*)(w1l + kbase + t * 512);
            acc[t] = __builtin_amdgcn_mfma_f32_16x16x32_bf16(ahi, bhi, acc[t], 0, 0, 0);
            acc[t] = __builtin_amdgcn_mfma_f32_16x16x32_bf16(alo, bhi, acc[t], 0, 0, 0);
            acc[t] = __builtin_amdgcn_mfma_f32_16x16x32_bf16(ahi, blo, acc[t], 0, 0, 0);
        }
    }

    // ---- h1 -> LDS (bf16 hi/lo, XOR-swizzled rows) ----
    char* ph = (char*)&sh1[wv][0][0];
    char* pl = (char*)&sh1[wv][1][0];
    #pragma unroll
    for (int t = 0; t < 16; ++t) {
        const int col2 = (t * 16 + r16) * 2;
        #pragma unroll
        for (int r = 0; r < 4; ++r) {
            const int row = kg * 4 + r;
            float h = fmaxf(acc[t][r] + bias1v[t], 0.f);
            const ushort hh = f2bf(h);
            const ushort hl = f2bf(h - bf2f(hh));
            const int byte = row * 512 + (col2 ^ ((row & 7) << 4));
            *(ushort*)(ph + byte) = hh;
            *(ushort*)(pl + byte) = hl;
        }
    }
    __threadfence_block();

    // ---- layer 2: h2 = relu(h1 W2 + b2) ----
    const ushort* w2h = W2h + n * (8 * 256 * 32);
    const ushort* w2l = W2l + n * (8 * 256 * 32);
    float bias2v[16];
    #pragma unroll
    for (int t = 0; t < 16; ++t) bias2v[t] = b2[n * HDIM + t * 16 + r16];

    f32x4 acc2[16];
    #pragma unroll
    for (int t = 0; t < 16; ++t) acc2[t] = (f32x4){0.f, 0.f, 0.f, 0.f};

    for (int kc = 0; kc < 8; ++kc) {
        const int kb = kc * 64 + kg * 16;  // byte offset of this lane's 8 k's
        const int abyte = r16 * 512 + (kb ^ ((r16 & 7) << 4));
        const short8 ahi = *(const short8*)(ph + abyte);
        const short8 alo = *(const short8*)(pl + abyte);
        const int kbase = kc * 8192 + laneB;
        #pragma unroll
        for (int t = 0; t < 16; ++t) {
            const short8 bhi = *(const short8*)(w2h + kbase + t * 512);
            const short8 blo = *(const short8*)(w2l + kbase + t * 512);
            acc2[t] = __builtin_amdgcn_mfma_f32_16x16x32_bf16(ahi, bhi, acc2[t], 0, 0, 0);
            acc2[t] = __builtin_amdgcn_mfma_f32_16x16x32_bf16(alo, bhi, acc2[t], 0, 0, 0);
            acc2[t] = __builtin_amdgcn_mfma_f32_16x16x32_bf16(ahi, blo, acc2[t], 0, 0, 0);
        }
    }

    // ---- layer 3: out = h2 W3 + b3 (O=2), 16-lane shuffle reduce ----
    float p0[4] = {0.f, 0.f, 0.f, 0.f};
    float p1[4] = {0.f, 0.f, 0.f, 0.f};
    #pragma unroll
    for (int t = 0; t < 16; ++t) {
        const float2 w3v = *(const float2*)(W3 + (size_t)(n * HDIM + t * 16 + r16) * 2);
        #pragma unroll
        for (int r = 0; r < 4; ++r) {
            const float v = fmaxf(acc2[t][r] + bias2v[t], 0.f);
            p0[r] = fmaf(v, w3v.x, p0[r]);
            p1[r] = fmaf(v, w3v.y, p1[r]);
        }
    }
    #pragma unroll
    for (int off = 8; off >= 1; off >>= 1) {
        #pragma unroll
        for (int r = 0; r < 4; ++r) {
            p0[r] += __shfl_xor(p0[r], off);
            p1[r] += __shfl_xor(p1[r], off);
        }
    }
    if (r16 == 0) {
        const float bx = b3[n * 2], by = b3[n * 2 + 1];
        #pragma unroll
        for (int r = 0; r < 4; ++r) {
            const int tg = tbase + kg * 4 + r;
            if (tg < cnt) {
                const int tk = lists[n * TOK_TOTAL + tg];
                *(float2*)(out + (size_t)tk * 2) = make_float2(p0[r] + bx, p1[r] + by);
            }
        }
    }
}

// ------------------------------------------------- fallback (round 1) ----
#define CHUNKS 16
#define CHUNK (TOK_TOTAL / CHUNKS)
#define TILE 32
#define KB 16

__global__ __launch_bounds__(256) void mth_routed_fp32(
    const float* __restrict__ X, const int* __restrict__ tasks,
    const int* __restrict__ lut,
    const float* __restrict__ W1, const float* __restrict__ b1,
    const float* __restrict__ W2, const float* __restrict__ b2,
    const float* __restrict__ W3, const float* __restrict__ b3,
    float* __restrict__ out)
{
    const int n = blockIdx.x, chnk = blockIdx.y, tid = threadIdx.x;
    const int lane = tid & 63, wv = tid >> 6, tx = tid & 31, ty = tid >> 5;
    __shared__ int s_list[CHUNK];
    __shared__ int s_cnt[8];
    __shared__ __align__(16) float s_x[KB][TILE];
    __shared__ __align__(16) float s_w[KB][HDIM];
    __shared__ __align__(16) float s_h[HDIM][TILE];
    const int base = chnk * CHUNK;
    int mytok[2], mypre[2], myseg[2]; bool mymatch[2];
    #pragma unroll
    for (int i = 0; i < 2; ++i) {
        const int tok = base + i * 256 + tid;
        const int task = tasks[tok];
        const int hidx = (task >= 0 && task < VOCAB) ? lut[task] : -1;
        const bool match = (hidx == n);
        const unsigned long long mask = __ballot(match);
        mytok[i] = tok; mymatch[i] = match;
        mypre[i] = __popcll(mask & ((1ULL << lane) - 1ULL));
        myseg[i] = i * 4 + wv;
        if (lane == 0) s_cnt[i * 4 + wv] = (int)__popcll(mask);
    }
    __syncthreads();
    int total = 0; int myoff[2] = {0, 0};
    #pragma unroll
    for (int s2 = 0; s2 < 8; ++s2) {
        if (s2 == myseg[0]) myoff[0] = total;
        if (s2 == myseg[1]) myoff[1] = total;
        total += s_cnt[s2];
    }
    #pragma unroll
    for (int i = 0; i < 2; ++i)
        if (mymatch[i]) s_list[myoff[i] + mypre[i]] = mytok[i];
    __syncthreads();
    const int ntok = total;
    if (ntok == 0) return;
    float bias1[8], bias2[8];
    #pragma unroll
    for (int j = 0; j < 8; ++j) {
        bias1[j] = b1[n * HDIM + tx * 8 + j];
        bias2[j] = b2[n * HDIM + tx * 8 + j];
    }
    float w3v[16];
    #pragma unroll
    for (int j = 0; j < 16; ++j) w3v[j] = W3[n * HDIM * ODIM + tx * 8 * ODIM + j];
    const float b3v0 = b3[n * ODIM + 0], b3v1 = b3[n * ODIM + 1];
    const float* W1n = W1 + (size_t)n * DDIM * HDIM;
    const float* W2n = W2 + (size_t)n * HDIM * HDIM;
    for (int ts = 0; ts < ntok; ts += TILE) {
        const int m = min(TILE, ntok - ts);
        float acc[4][8];
        #pragma unroll
        for (int t = 0; t < 4; ++t)
            #pragma unroll
            for (int j = 0; j < 8; ++j) acc[t][j] = 0.f;
        for (int kc = 0; kc < DDIM / KB; ++kc) {
            const float4* src = (const float4*)(W1n + kc * KB * HDIM);
            float4* dst = (float4*)s_w;
            #pragma unroll
            for (int p = 0; p < 4; ++p) dst[tid + p * 256] = src[tid + p * 256];
            #pragma unroll
            for (int p = 0; p < 2; ++p) {
                const int e = tid + p * 256;
                const int dd = e >> 5, t = e & 31;
                float v = 0.f;
                if (t < m) v = X[(size_t)s_list[ts + t] * DDIM + kc * KB + dd];
                s_x[dd][t] = v;
            }
            __syncthreads();
            #pragma unroll
            for (int dd = 0; dd < KB; ++dd) {
                const float4 xa = *(const float4*)&s_x[dd][ty * 4];
                const float4 wa = *(const float4*)&s_w[dd][tx * 8];
                const float4 wb = *(const float4*)&s_w[dd][tx * 8 + 4];
                const float xs[4] = {xa.x, xa.y, xa.z, xa.w};
                const float ws[8] = {wa.x, wa.y, wa.z, wa.w, wb.x, wb.y, wb.z, wb.w};
                #pragma unroll
                for (int t = 0; t < 4; ++t)
                    #pragma unroll
                    for (int j = 0; j < 8; ++j) acc[t][j] = fmaf(xs[t], ws[j], acc[t][j]);
            }
            __syncthreads();
        }
        #pragma unroll
        for (int j = 0; j < 8; ++j) {
            float4 v;
            v.x = fmaxf(acc[0][j] + bias1[j], 0.f);
            v.y = fmaxf(acc[1][j] + bias1[j], 0.f);
            v.z = fmaxf(acc[2][j] + bias1[j], 0.f);
            v.w = fmaxf(acc[3][j] + bias1[j], 0.f);
            *(float4*)&s_h[tx * 8 + j][ty * 4] = v;
        }
        __syncthreads();
        float acc2[4][8];
        #pragma unroll
        for (int t = 0; t < 4; ++t)
            #pragma unroll
            for (int j = 0; j < 8; ++j) acc2[t][j] = 0.f;
        for (int kc = 0; kc < HDIM / KB; ++kc) {
            const float4* src = (const float4*)(W2n + kc * KB * HDIM);
            float4* dst = (float4*)s_w;
            #pragma unroll
            for (int p = 0; p < 4; ++p) dst[tid + p * 256] = src[tid + p * 256];
            __syncthreads();
            #pragma unroll
            for (int dd = 0; dd < KB; ++dd) {
                const int k = kc * KB + dd;
                const float4 xa = *(const float4*)&s_h[k][ty * 4];
                const float4 wa = *(const float4*)&s_w[dd][tx * 8];
                const float4 wb = *(const float4*)&s_w[dd][tx * 8 + 4];
                const float xs[4] = {xa.x, xa.y, xa.z, xa.w};
                const float ws[8] = {wa.x, wa.y, wa.z, wa.w, wb.x, wb.y, wb.z, wb.w};
                #pragma unroll
                for (int t = 0; t < 4; ++t)
                    #pragma unroll
                    for (int j = 0; j < 8; ++j) acc2[t][j] = fmaf(xs[t], ws[j], acc2[t][j]);
            }
            __syncthreads();
        }
        float p0[4] = {0.f, 0.f, 0.f, 0.f}, p1[4] = {0.f, 0.f, 0.f, 0.f};
        #pragma unroll
        for (int t = 0; t < 4; ++t)
            #pragma unroll
            for (int j = 0; j < 8; ++j) {
                const float v = fmaxf(acc2[t][j] + bias2[j], 0.f);
                p0[t] = fmaf(v, w3v[j * 2 + 0], p0[t]);
                p1[t] = fmaf(v, w3v[j * 2 + 1], p1[t]);
            }
        #pragma unroll
        for (int off = 16; off > 0; off >>= 1)
            #pragma unroll
            for (int t = 0; t < 4; ++t) {
                p0[t] += __shfl_xor(p0[t], off);
                p1[t] += __shfl_xor(p1[t], off);
            }
        if (tx == 0) {
            #pragma unroll
            for (int t = 0; t < 4; ++t) {
                const int ti = ty * 4 + t;
                if (ti < m) {
                    const int tok = s_list[ts + ti];
                    out[tok * ODIM + 0] = p0[t] + b3v0;
                    out[tok * ODIM + 1] = p1[t] + b3v1;
                }
            }
        }
        __syncthreads();
    }
}

// -------------------------------------------------------------- launch ----
extern "C" void kernel_launch(void* const* d_in, const int* in_sizes, int n_in,
                              void* d_out, int out_size, void* d_ws, size_t ws_size,
                              hipStream_t stream) {
    const float* X     = (const float*)d_in[0];
    const int*   tasks = (const int*)d_in[1];
    const int*   lut   = (const int*)d_in[2];
    const float* W1    = (const float*)d_in[3];
    const float* b1    = (const float*)d_in[4];
    const float* W2    = (const float*)d_in[5];
    const float* b2    = (const float*)d_in[6];
    const float* W3    = (const float*)d_in[7];
    const float* b3    = (const float*)d_in[8];
    float* out = (float*)d_out;

    hipMemsetAsync(out, 0, (size_t)out_size * sizeof(float), stream);

    // workspace layout (bytes)
    const size_t OFF_COUNTS = 0;                      // 16 ints
    const size_t OFF_LISTS  = 64;                     // 16*8192 ints = 512 KB
    const size_t OFF_W1H    = OFF_LISTS + (size_t)NHEADS * TOK_TOTAL * 4;  // 524352
    const size_t NW1        = (size_t)NHEADS * DDIM * HDIM;                // 2M
    const size_t NW2        = (size_t)NHEADS * HDIM * HDIM;                // 1M
    const size_t OFF_W1L    = OFF_W1H + NW1 * 2;
    const size_t OFF_W2H    = OFF_W1L + NW1 * 2;
    const size_t OFF_W2L    = OFF_W2H + NW2 * 2;
    const size_t NEED       = OFF_W2L + NW2 * 2;      // ~13.1 MB

    if (ws_size < NEED) {
        dim3 grid(NHEADS, CHUNKS);
        mth_routed_fp32<<<grid, 256, 0, stream>>>(X, tasks, lut, W1, b1, W2, b2, W3, b3, out);
        return;
    }

    char* ws = (char*)d_ws;
    int*    counts = (int*)(ws + OFF_COUNTS);
    int*    lists  = (int*)(ws + OFF_LISTS);
    ushort* W1h    = (ushort*)(ws + OFF_W1H);
    ushort* W1l    = (ushort*)(ws + OFF_W1L);
    ushort* W2h    = (ushort*)(ws + OFF_W2H);
    ushort* W2l    = (ushort*)(ws + OFF_W2L);

    hipMemsetAsync(counts, 0, 16 * sizeof(int), stream);

    const int prep_threads = (int)(NW1 + NW2);        // 3,145,728
    mth_prep<<<prep_threads / 256, 256, 0, stream>>>(W1, W2, W1h, W1l, W2h, W2l);
    mth_compact<<<TOK_TOTAL / 256, 256, 0, stream>>>(tasks, lut, counts, lists);
    dim3 grid(NHEADS, 128);
    mth_mfma<<<grid, 256, 0, stream>>>(X, counts, lists, W1h, W1l, W2h, W2l,
                                       b1, b2, W3, b3, out);
}

// Round 3
// 87.128 us; speedup vs baseline: 2.0566x; 1.5799x over previous
//
#include <hip/hip_runtime.h>

#define TOK_TOTAL 8192
#define DDIM 512
#define HDIM 256
#define ODIM 2
#define NHEADS 16
#define VOCAB 1024

typedef __attribute__((ext_vector_type(8))) short short8;
typedef __attribute__((ext_vector_type(4))) float f32x4;

__device__ inline ushort f2bf(float f) {
    uint u = __float_as_uint(f);
    uint r = (u + 0x7fffu + ((u >> 16) & 1u)) >> 16;
    return (ushort)r;
}
__device__ inline float bf2f(ushort h) { return __uint_as_float(((uint)h) << 16); }

// ---------------------------------------------------------------- prep ----
// W1/W2 fp32 -> bf16 hi/lo planes, layout [n][kc][c][ks] (ks = k%32).
// Coalesced via LDS 32x257 transpose. 384 blocks x 256 threads.
__global__ __launch_bounds__(256) void mth_prep(
    const float* __restrict__ W1, const float* __restrict__ W2,
    ushort* __restrict__ W1h, ushort* __restrict__ W1l,
    ushort* __restrict__ W2h, ushort* __restrict__ W2l)
{
    __shared__ float s[32][257];
    const int b = blockIdx.x, t = threadIdx.x;
    const float* src;
    ushort *dh, *dl;
    if (b < 256) {
        const int n = b >> 4, kc = b & 15;
        src = W1 + (size_t)(n * 16 + kc) * 8192;
        dh = W1h + (size_t)(n * 16 + kc) * 8192;
        dl = W1l + (size_t)(n * 16 + kc) * 8192;
    } else {
        const int b2 = b - 256, n = b2 >> 3, kc = b2 & 7;
        src = W2 + (size_t)(n * 8 + kc) * 8192;
        dh = W2h + (size_t)(n * 8 + kc) * 8192;
        dl = W2l + (size_t)(n * 8 + kc) * 8192;
    }
    #pragma unroll
    for (int i = 0; i < 8; ++i) {
        const int q = t + i * 256;
        const float4 f = ((const float4*)src)[q];
        const int k = q >> 6, c4 = (q & 63) * 4;
        s[k][c4] = f.x; s[k][c4 + 1] = f.y; s[k][c4 + 2] = f.z; s[k][c4 + 3] = f.w;
    }
    __syncthreads();
    const int c = t;
    #pragma unroll
    for (int g = 0; g < 4; ++g) {
        short8 hb, lb;
        #pragma unroll
        for (int j = 0; j < 8; ++j) {
            const float v = s[g * 8 + j][c];
            const ushort hi = f2bf(v);
            hb[j] = (short)hi;
            lb[j] = (short)f2bf(v - bf2f(hi));
        }
        *(short8*)(dh + c * 32 + g * 8) = hb;
        *(short8*)(dl + c * 32 + g * 8) = lb;
    }
}

// ------------------------------------------------------------- compact ----
__global__ __launch_bounds__(256) void mth_compact(
    const int* __restrict__ tasks, const int* __restrict__ lut,
    int* __restrict__ counts, int* __restrict__ lists)
{
    const int tok = blockIdx.x * 256 + threadIdx.x;
    const int l = threadIdx.x & 63;
    const int task = tasks[tok];
    const int h = (task >= 0 && task < VOCAB) ? lut[task] : -1;
    const unsigned long long lt = (1ULL << l) - 1ULL;
    for (int n = 0; n < NHEADS; ++n) {
        const unsigned long long m = __ballot(h == n);
        if (m == 0ULL) continue;
        const int leader = (int)__ffsll((unsigned long long)m) - 1;
        int base = 0;
        if (l == leader) base = atomicAdd(&counts[n], (int)__popcll(m));
        base = __shfl(base, leader);
        if (h == n) lists[n * TOK_TOTAL + base + (int)__popcll(m & lt)] = tok;
    }
}

// ----------------------------------------------------------------- mlp ----
// Block = 8 waves = 32 tokens x 256 cols; wave w owns cols [w*32, w*32+32).
// A staged in LDS (lane-fragment-major, XOR-swizzled); B streamed from L2.
__global__ __launch_bounds__(512) void mth_mlp(
    const float* __restrict__ X, const int* __restrict__ counts,
    const int* __restrict__ lists,
    const ushort* __restrict__ W1h, const ushort* __restrict__ W1l,
    const ushort* __restrict__ W2h, const ushort* __restrict__ W2l,
    const float* __restrict__ b1, const float* __restrict__ b2,
    const float* __restrict__ W3, const float* __restrict__ b3,
    float* __restrict__ out)
{
    __shared__ ushort Ah[16][2][64][8];   // 32 KB  [kc][tf][lane][pos]
    __shared__ ushort Al[16][2][64][8];   // 32 KB
    __shared__ ushort Hh[8][2][64][8];    // 16 KB  [kc2][tf][lane][pos]
    __shared__ ushort Hl[8][2][64][8];    // 16 KB
    __shared__ float  part[8][32][2];     //  2 KB

    const int b = blockIdx.x;
    const int n = ((b & 7) << 1) | ((b >> 3) & 1);  // XCD-clustered heads
    const int tile0 = b >> 4;                        // 0..31, stride 32

    const int tid = threadIdx.x;
    const int w   = tid >> 6;
    const int l   = tid & 63;
    const int r16 = l & 15;
    const int kg  = l >> 4;

    const int cnt = counts[n];
    if (cnt == 0) return;

    const int cbase = w * 32;
    const float bias1a = b1[n * HDIM + cbase + r16];
    const float bias1b = b1[n * HDIM + cbase + 16 + r16];
    const float bias2a = b2[n * HDIM + cbase + r16];
    const float bias2b = b2[n * HDIM + cbase + 16 + r16];
    const float2 w3a = *(const float2*)(W3 + (size_t)(n * HDIM + cbase + r16) * 2);
    const float2 w3b = *(const float2*)(W3 + (size_t)(n * HDIM + cbase + 16 + r16) * 2);

    const ushort* w1hn = W1h + (size_t)n * (16 * 8192);
    const ushort* w1ln = W1l + (size_t)n * (16 * 8192);
    const ushort* w2hn = W2h + (size_t)n * (8 * 8192);
    const ushort* w2ln = W2l + (size_t)n * (8 * 8192);
    const int boff = (cbase + r16) * 32 + kg * 8;   // c*32 + ks within a kc-plane

    const int stok = tid >> 4;          // stage: token 0..31
    const int skc  = tid & 15;          // stage: kc 0..15
    const int stf  = stok >> 4, srr = stok & 15;
    const int slsw = (skc & 3) << 2;
    const int listbase = n * TOK_TOTAL;

    for (int T = tile0; T * 32 < cnt; T += 32) {
        // ---- stage A: X tile -> LDS hi/lo, fragment order ----
        {
            const int tokidx = min(T * 32 + stok, cnt - 1);
            const int tok = lists[listbase + tokidx];
            const float* xp = X + (size_t)tok * DDIM + skc * 32;
            #pragma unroll
            for (int g = 0; g < 4; ++g) {
                const float4 f0 = *(const float4*)(xp + g * 8);
                const float4 f1 = *(const float4*)(xp + g * 8 + 4);
                const float vv[8] = {f0.x, f0.y, f0.z, f0.w, f1.x, f1.y, f1.z, f1.w};
                short8 hb, lb;
                #pragma unroll
                for (int j = 0; j < 8; ++j) {
                    const ushort hi = f2bf(vv[j]);
                    hb[j] = (short)hi;
                    lb[j] = (short)f2bf(vv[j] - bf2f(hi));
                }
                const int lane2 = (g * 16 + srr) ^ slsw;
                *(short8*)&Ah[skc][stf][lane2][0] = hb;
                *(short8*)&Al[skc][stf][lane2][0] = lb;
            }
        }
        __syncthreads();

        // ---- layer 1: h1 = relu(X W1 + b1) ----
        f32x4 acc[2][2];
        #pragma unroll
        for (int tf = 0; tf < 2; ++tf)
            #pragma unroll
            for (int cf = 0; cf < 2; ++cf) acc[tf][cf] = (f32x4){0.f, 0.f, 0.f, 0.f};

        #pragma unroll 4
        for (int kc = 0; kc < 16; ++kc) {
            const int lr = l ^ ((kc & 3) << 2);
            const short8 ah0 = *(const short8*)&Ah[kc][0][lr][0];
            const short8 al0 = *(const short8*)&Al[kc][0][lr][0];
            const short8 ah1 = *(const short8*)&Ah[kc][1][lr][0];
            const short8 al1 = *(const short8*)&Al[kc][1][lr][0];
            const int base = kc * 8192 + boff;
            const short8 bh0 = *(const short8*)(w1hn + base);
            const short8 bh1 = *(const short8*)(w1hn + base + 512);
            const short8 bl0 = *(const short8*)(w1ln + base);
            const short8 bl1 = *(const short8*)(w1ln + base + 512);
            acc[0][0] = __builtin_amdgcn_mfma_f32_16x16x32_bf16(ah0, bh0, acc[0][0], 0, 0, 0);
            acc[0][0] = __builtin_amdgcn_mfma_f32_16x16x32_bf16(al0, bh0, acc[0][0], 0, 0, 0);
            acc[0][0] = __builtin_amdgcn_mfma_f32_16x16x32_bf16(ah0, bl0, acc[0][0], 0, 0, 0);
            acc[0][1] = __builtin_amdgcn_mfma_f32_16x16x32_bf16(ah0, bh1, acc[0][1], 0, 0, 0);
            acc[0][1] = __builtin_amdgcn_mfma_f32_16x16x32_bf16(al0, bh1, acc[0][1], 0, 0, 0);
            acc[0][1] = __builtin_amdgcn_mfma_f32_16x16x32_bf16(ah0, bl1, acc[0][1], 0, 0, 0);
            acc[1][0] = __builtin_amdgcn_mfma_f32_16x16x32_bf16(ah1, bh0, acc[1][0], 0, 0, 0);
            acc[1][0] = __builtin_amdgcn_mfma_f32_16x16x32_bf16(al1, bh0, acc[1][0], 0, 0, 0);
            acc[1][0] = __builtin_amdgcn_mfma_f32_16x16x32_bf16(ah1, bl0, acc[1][0], 0, 0, 0);
            acc[1][1] = __builtin_amdgcn_mfma_f32_16x16x32_bf16(ah1, bh1, acc[1][1], 0, 0, 0);
            acc[1][1] = __builtin_amdgcn_mfma_f32_16x16x32_bf16(al1, bh1, acc[1][1], 0, 0, 0);
            acc[1][1] = __builtin_amdgcn_mfma_f32_16x16x32_bf16(ah1, bl1, acc[1][1], 0, 0, 0);
        }

        // ---- h1 -> LDS (hi/lo), wave w produces layer-2 k-slice kc2 = w ----
        #pragma unroll
        for (int tf = 0; tf < 2; ++tf) {
            #pragma unroll
            for (int cf = 0; cf < 2; ++cf) {
                const float bias = cf ? bias1b : bias1a;
                const int lhi = (cf * 2 + (r16 >> 3)) * 16 + kg * 4;
                #pragma unroll
                for (int j = 0; j < 4; ++j) {
                    const float v = fmaxf(acc[tf][cf][j] + bias, 0.f);
                    const ushort hh = f2bf(v);
                    const ushort hl = f2bf(v - bf2f(hh));
                    Hh[w][tf][lhi + j][r16 & 7] = hh;
                    Hl[w][tf][lhi + j][r16 & 7] = hl;
                }
            }
        }
        __syncthreads();

        // ---- layer 2: h2 = relu(h1 W2 + b2) ----
        f32x4 acc2[2][2];
        #pragma unroll
        for (int tf = 0; tf < 2; ++tf)
            #pragma unroll
            for (int cf = 0; cf < 2; ++cf) acc2[tf][cf] = (f32x4){0.f, 0.f, 0.f, 0.f};

        #pragma unroll 4
        for (int kc = 0; kc < 8; ++kc) {
            const short8 ah0 = *(const short8*)&Hh[kc][0][l][0];
            const short8 al0 = *(const short8*)&Hl[kc][0][l][0];
            const short8 ah1 = *(const short8*)&Hh[kc][1][l][0];
            const short8 al1 = *(const short8*)&Hl[kc][1][l][0];
            const int base = kc * 8192 + boff;
            const short8 bh0 = *(const short8*)(w2hn + base);
            const short8 bh1 = *(const short8*)(w2hn + base + 512);
            const short8 bl0 = *(const short8*)(w2ln + base);
            const short8 bl1 = *(const short8*)(w2ln + base + 512);
            acc2[0][0] = __builtin_amdgcn_mfma_f32_16x16x32_bf16(ah0, bh0, acc2[0][0], 0, 0, 0);
            acc2[0][0] = __builtin_amdgcn_mfma_f32_16x16x32_bf16(al0, bh0, acc2[0][0], 0, 0, 0);
            acc2[0][0] = __builtin_amdgcn_mfma_f32_16x16x32_bf16(ah0, bl0, acc2[0][0], 0, 0, 0);
            acc2[0][1] = __builtin_amdgcn_mfma_f32_16x16x32_bf16(ah0, bh1, acc2[0][1], 0, 0, 0);
            acc2[0][1] = __builtin_amdgcn_mfma_f32_16x16x32_bf16(al0, bh1, acc2[0][1], 0, 0, 0);
            acc2[0][1] = __builtin_amdgcn_mfma_f32_16x16x32_bf16(ah0, bl1, acc2[0][1], 0, 0, 0);
            acc2[1][0] = __builtin_amdgcn_mfma_f32_16x16x32_bf16(ah1, bh0, acc2[1][0], 0, 0, 0);
            acc2[1][0] = __builtin_amdgcn_mfma_f32_16x16x32_bf16(al1, bh0, acc2[1][0], 0, 0, 0);
            acc2[1][0] = __builtin_amdgcn_mfma_f32_16x16x32_bf16(ah1, bl0, acc2[1][0], 0, 0, 0);
            acc2[1][1] = __builtin_amdgcn_mfma_f32_16x16x32_bf16(ah1, bh1, acc2[1][1], 0, 0, 0);
            acc2[1][1] = __builtin_amdgcn_mfma_f32_16x16x32_bf16(al1, bh1, acc2[1][1], 0, 0, 0);
            acc2[1][1] = __builtin_amdgcn_mfma_f32_16x16x32_bf16(ah1, bl1, acc2[1][1], 0, 0, 0);
        }

        // ---- layer 3: partial dot over this wave's 32 cols ----
        float p[2][4][2];
        #pragma unroll
        for (int tf = 0; tf < 2; ++tf)
            #pragma unroll
            for (int j = 0; j < 4; ++j) { p[tf][j][0] = 0.f; p[tf][j][1] = 0.f; }
        #pragma unroll
        for (int tf = 0; tf < 2; ++tf) {
            #pragma unroll
            for (int cf = 0; cf < 2; ++cf) {
                const float bias = cf ? bias2b : bias2a;
                const float w3x = cf ? w3b.x : w3a.x;
                const float w3y = cf ? w3b.y : w3a.y;
                #pragma unroll
                for (int j = 0; j < 4; ++j) {
                    const float v = fmaxf(acc2[tf][cf][j] + bias, 0.f);
                    p[tf][j][0] = fmaf(v, w3x, p[tf][j][0]);
                    p[tf][j][1] = fmaf(v, w3y, p[tf][j][1]);
                }
            }
        }
        #pragma unroll
        for (int off = 8; off >= 1; off >>= 1) {
            #pragma unroll
            for (int tf = 0; tf < 2; ++tf)
                #pragma unroll
                for (int j = 0; j < 4; ++j) {
                    p[tf][j][0] += __shfl_xor(p[tf][j][0], off);
                    p[tf][j][1] += __shfl_xor(p[tf][j][1], off);
                }
        }
        if (r16 == 0) {
            #pragma unroll
            for (int tf = 0; tf < 2; ++tf)
                #pragma unroll
                for (int j = 0; j < 4; ++j) {
                    const int tkn = tf * 16 + kg * 4 + j;
                    part[w][tkn][0] = p[tf][j][0];
                    part[w][tkn][1] = p[tf][j][1];
                }
        }
        __syncthreads();

        // ---- cross-wave reduce + write ----
        if (tid < 64) {
            const int tk = tid >> 1, o = tid & 1;
            if (T * 32 + tk < cnt) {
                float s = 0.f;
                #pragma unroll
                for (int w2 = 0; w2 < 8; ++w2) s += part[w2][tk][o];
                const int tok = lists[listbase + T * 32 + tk];
                out[(size_t)tok * 2 + o] = s + b3[n * 2 + o];
            }
        }
        __syncthreads();
    }
}

// ------------------------------------------------- fallback (round 1) ----
#define CHUNKS 16
#define CHUNK (TOK_TOTAL / CHUNKS)
#define TILE 32
#define KB 16

__global__ __launch_bounds__(256) void mth_routed_fp32(
    const float* __restrict__ X, const int* __restrict__ tasks,
    const int* __restrict__ lut,
    const float* __restrict__ W1, const float* __restrict__ b1,
    const float* __restrict__ W2, const float* __restrict__ b2,
    const float* __restrict__ W3, const float* __restrict__ b3,
    float* __restrict__ out)
{
    const int n = blockIdx.x, chnk = blockIdx.y, tid = threadIdx.x;
    const int lane = tid & 63, wv = tid >> 6, tx = tid & 31, ty = tid >> 5;
    __shared__ int s_list[CHUNK];
    __shared__ int s_cnt[8];
    __shared__ __align__(16) float s_x[KB][TILE];
    __shared__ __align__(16) float s_w[KB][HDIM];
    __shared__ __align__(16) float s_h[HDIM][TILE];
    const int base = chnk * CHUNK;
    int mytok[2], mypre[2], myseg[2]; bool mymatch[2];
    #pragma unroll
    for (int i = 0; i < 2; ++i) {
        const int tok = base + i * 256 + tid;
        const int task = tasks[tok];
        const int hidx = (task >= 0 && task < VOCAB) ? lut[task] : -1;
        const bool match = (hidx == n);
        const unsigned long long mask = __ballot(match);
        mytok[i] = tok; mymatch[i] = match;
        mypre[i] = __popcll(mask & ((1ULL << lane) - 1ULL));
        myseg[i] = i * 4 + wv;
        if (lane == 0) s_cnt[i * 4 + wv] = (int)__popcll(mask);
    }
    __syncthreads();
    int total = 0; int myoff[2] = {0, 0};
    #pragma unroll
    for (int s2 = 0; s2 < 8; ++s2) {
        if (s2 == myseg[0]) myoff[0] = total;
        if (s2 == myseg[1]) myoff[1] = total;
        total += s_cnt[s2];
    }
    #pragma unroll
    for (int i = 0; i < 2; ++i)
        if (mymatch[i]) s_list[myoff[i] + mypre[i]] = mytok[i];
    __syncthreads();
    const int ntok = total;
    if (ntok == 0) return;
    float bias1[8], bias2[8];
    #pragma unroll
    for (int j = 0; j < 8; ++j) {
        bias1[j] = b1[n * HDIM + tx * 8 + j];
        bias2[j] = b2[n * HDIM + tx * 8 + j];
    }
    float w3v[16];
    #pragma unroll
    for (int j = 0; j < 16; ++j) w3v[j] = W3[n * HDIM * ODIM + tx * 8 * ODIM + j];
    const float b3v0 = b3[n * ODIM + 0], b3v1 = b3[n * ODIM + 1];
    const float* W1n = W1 + (size_t)n * DDIM * HDIM;
    const float* W2n = W2 + (size_t)n * HDIM * HDIM;
    for (int ts = 0; ts < ntok; ts += TILE) {
        const int m = min(TILE, ntok - ts);
        float acc[4][8];
        #pragma unroll
        for (int t = 0; t < 4; ++t)
            #pragma unroll
            for (int j = 0; j < 8; ++j) acc[t][j] = 0.f;
        for (int kc = 0; kc < DDIM / KB; ++kc) {
            const float4* src = (const float4*)(W1n + kc * KB * HDIM);
            float4* dst = (float4*)s_w;
            #pragma unroll
            for (int p = 0; p < 4; ++p) dst[tid + p * 256] = src[tid + p * 256];
            #pragma unroll
            for (int p = 0; p < 2; ++p) {
                const int e = tid + p * 256;
                const int dd = e >> 5, t = e & 31;
                float v = 0.f;
                if (t < m) v = X[(size_t)s_list[ts + t] * DDIM + kc * KB + dd];
                s_x[dd][t] = v;
            }
            __syncthreads();
            #pragma unroll
            for (int dd = 0; dd < KB; ++dd) {
                const float4 xa = *(const float4*)&s_x[dd][ty * 4];
                const float4 wa = *(const float4*)&s_w[dd][tx * 8];
                const float4 wb = *(const float4*)&s_w[dd][tx * 8 + 4];
                const float xs[4] = {xa.x, xa.y, xa.z, xa.w};
                const float ws[8] = {wa.x, wa.y, wa.z, wa.w, wb.x, wb.y, wb.z, wb.w};
                #pragma unroll
                for (int t = 0; t < 4; ++t)
                    #pragma unroll
                    for (int j = 0; j < 8; ++j) acc[t][j] = fmaf(xs[t], ws[j], acc[t][j]);
            }
            __syncthreads();
        }
        #pragma unroll
        for (int j = 0; j < 8; ++j) {
            float4 v;
            v.x = fmaxf(acc[0][j] + bias1[j], 0.f);
            v.y = fmaxf(acc[1][j] + bias1[j], 0.f);
            v.z = fmaxf(acc[2][j] + bias1[j], 0.f);
            v.w = fmaxf(acc[3][j] + bias1[j], 0.f);
            *(float4*)&s_h[tx * 8 + j][ty * 4] = v;
        }
        __syncthreads();
        float acc2[4][8];
        #pragma unroll
        for (int t = 0; t < 4; ++t)
            #pragma unroll
            for (int j = 0; j < 8; ++j) acc2[t][j] = 0.f;
        for (int kc = 0; kc < HDIM / KB; ++kc) {
            const float4* src = (const float4*)(W2n + kc * KB * HDIM);
            float4* dst = (float4*)s_w;
            #pragma unroll
            for (int p = 0; p < 4; ++p) dst[tid + p * 256] = src[tid + p * 256];
            __syncthreads();
            #pragma unroll
            for (int dd = 0; dd < KB; ++dd) {
                const int k = kc * KB + dd;
                const float4 xa = *(const float4*)&s_h[k][ty * 4];
                const float4 wa = *(const float4*)&s_w[dd][tx * 8];
                const float4 wb = *(const float4*)&s_w[dd][tx * 8 + 4];
                const float xs[4] = {xa.x, xa.y, xa.z, xa.w};
                const float ws[8] = {wa.x, wa.y, wa.z, wa.w, wb.x, wb.y, wb.z, wb.w};
                #pragma unroll
                for (int t = 0; t < 4; ++t)
                    #pragma unroll
                    for (int j = 0; j < 8; ++j) acc2[t][j] = fmaf(xs[t], ws[j], acc2[t][j]);
            }
            __syncthreads();
        }
        float p0[4] = {0.f, 0.f, 0.f, 0.f}, p1[4] = {0.f, 0.f, 0.f, 0.f};
        #pragma unroll
        for (int t = 0; t < 4; ++t)
            #pragma unroll
            for (int j = 0; j < 8; ++j) {
                const float v = fmaxf(acc2[t][j] + bias2[j], 0.f);
                p0[t] = fmaf(v, w3v[j * 2 + 0], p0[t]);
                p1[t] = fmaf(v, w3v[j * 2 + 1], p1[t]);
            }
        #pragma unroll
        for (int off = 16; off > 0; off >>= 1)
            #pragma unroll
            for (int t = 0; t < 4; ++t) {
                p0[t] += __shfl_xor(p0[t], off);
                p1[t] += __shfl_xor(p1[t], off);
            }
        if (tx == 0) {
            #pragma unroll
            for (int t = 0; t < 4; ++t) {
                const int ti = ty * 4 + t;
                if (ti < m) {
                    const int tok = s_list[ts + ti];
                    out[tok * ODIM + 0] = p0[t] + b3v0;
                    out[tok * ODIM + 1] = p1[t] + b3v1;
                }
            }
        }
        __syncthreads();
    }
}

// -------------------------------------------------------------- launch ----
extern "C" void kernel_launch(void* const* d_in, const int* in_sizes, int n_in,
                              void* d_out, int out_size, void* d_ws, size_t ws_size,
                              hipStream_t stream) {
    (void)in_sizes; (void)n_in;
    const float* X     = (const float*)d_in[0];
    const int*   tasks = (const int*)d_in[1];
    const int*   lut   = (const int*)d_in[2];
    const float* W1    = (const float*)d_in[3];
    const float* b1    = (const float*)d_in[4];
    const float* W2    = (const float*)d_in[5];
    const float* b2    = (const float*)d_in[6];
    const float* W3    = (const float*)d_in[7];
    const float* b3    = (const float*)d_in[8];
    float* out = (float*)d_out;

    hipMemsetAsync(out, 0, (size_t)out_size * sizeof(float), stream);

    const size_t OFF_COUNTS = 0;
    const size_t OFF_LISTS  = 64;
    const size_t OFF_W1H    = OFF_LISTS + (size_t)NHEADS * TOK_TOTAL * 4;
    const size_t NW1        = (size_t)NHEADS * DDIM * HDIM;   // 2M elems
    const size_t NW2        = (size_t)NHEADS * HDIM * HDIM;   // 1M elems
    const size_t OFF_W1L    = OFF_W1H + NW1 * 2;
    const size_t OFF_W2H    = OFF_W1L + NW1 * 2;
    const size_t OFF_W2L    = OFF_W2H + NW2 * 2;
    const size_t NEED       = OFF_W2L + NW2 * 2;              // ~13.1 MB

    if (ws_size < NEED) {
        dim3 grid(NHEADS, CHUNKS);
        mth_routed_fp32<<<grid, 256, 0, stream>>>(X, tasks, lut, W1, b1, W2, b2, W3, b3, out);
        return;
    }

    char* ws = (char*)d_ws;
    int*    counts = (int*)(ws + OFF_COUNTS);
    int*    lists  = (int*)(ws + OFF_LISTS);
    ushort* W1h    = (ushort*)(ws + OFF_W1H);
    ushort* W1l    = (ushort*)(ws + OFF_W1L);
    ushort* W2h    = (ushort*)(ws + OFF_W2H);
    ushort* W2l    = (ushort*)(ws + OFF_W2L);

    hipMemsetAsync(counts, 0, 16 * sizeof(int), stream);

    mth_prep<<<384, 256, 0, stream>>>(W1, W2, W1h, W1l, W2h, W2l);
    mth_compact<<<TOK_TOTAL / 256, 256, 0, stream>>>(tasks, lut, counts, lists);
    mth_mlp<<<512, 512, 0, stream>>>(X, counts, lists, W1h, W1l, W2h, W2l,
                                     b1, b2, W3, b3, out);
}